// Round 1
// baseline (682.368 us; speedup 1.0000x reference)
//
#include <hip/hip_runtime.h>

#define Hh 256
#define Ii 128
#define Bb 512
#define KF 384   // 128 (x) + 256 (hx) feature dim
#define KB 64    // k-block width per block
#define LDA 72   // padded LDS stride (elems) for sA / sP
#define LDB 40   // padded LDS stride for sB

typedef __attribute__((ext_vector_type(8))) short bf16x8;
typedef __attribute__((ext_vector_type(4))) float f32x4;
typedef unsigned short u16;
typedef unsigned int u32;

__device__ inline float bf2f(u16 u) { return __uint_as_float(((u32)u) << 16); }
__device__ inline u16 f2bf(float f) {
  u32 u = __float_as_uint(f);
  u += 0x7FFFu + ((u >> 16) & 1u);   // RNE
  return (u16)(u >> 16);
}
__device__ inline float sigm(float x) { return 1.0f / (1.0f + __expf(-x)); }
__device__ inline float tanh_f(float x) { return 1.0f - 2.0f / (1.0f + __expf(2.0f * x)); }

// ---------------- kernel 0: pack bf16 weights, transpose Vtinv, zero proj ----
__global__ void k_prep(const float* __restrict__ Wii, const float* __restrict__ Wif,
                       const float* __restrict__ Wig,
                       const float* __restrict__ Whi, const float* __restrict__ Whit,
                       const float* __restrict__ Whf, const float* __restrict__ Whft,
                       const float* __restrict__ Whc, const float* __restrict__ Whct,
                       const float* __restrict__ Vtinv,
                       u16* __restrict__ RW, u16* __restrict__ CW, u16* __restrict__ Vtt,
                       float* __restrict__ proj) {
  const int gid = blockIdx.x * blockDim.x + threadIdx.x;
  const int stride = gridDim.x * blockDim.x;
  const float* WX[3]  = {Wii, Wif, Wig};
  const float* WHr[3] = {Whi, Whf, Whc};
  const float* WHc2[3] = {Whit, Whft, Whct};
  const int total = 3 * Hh * KF;
  for (int idx = gid; idx < total; idx += stride) {
    int g = idx / (Hh * KF);
    int rem = idx - g * (Hh * KF);
    int h = rem / KF;
    int t = rem - h * KF;
    float a, c;
    if (t < Ii) { a = WX[g][h * Ii + t]; c = a; }
    else        { a = WHr[g][h * Hh + t - Ii]; c = WHc2[g][h * Hh + t - Ii]; }
    RW[idx] = f2bf(a);
    CW[idx] = f2bf(c);
  }
  for (int idx = gid; idx < Hh * Hh; idx += stride) {
    int ii = idx >> 8, kk = idx & 255;
    Vtt[idx] = f2bf(Vtinv[kk * Hh + ii]);   // Vtt[i][k] = Vtinv[k][i]
  }
  for (int idx = gid; idx < Bb * Hh; idx += stride) proj[idx] = 0.0f;
}

// ---------------- kernel 1: fused gates + cell + down-projection -------------
// grid: 2048 blocks = (b = blk>>2) x (k0 = (blk&3)*64); 256 threads = 4 waves.
// Each block: z tile 256(j) x 64(k) per gate via MFMA, gate-sequential with a
// single LDS p-buffer; then M[i,j] = sum_k Vt_t[i,k] c[j,k] via MFMA, Uinv-
// weighted reduce over j -> atomicAdd partial proj[b,i].
__global__ __launch_bounds__(256, 2) void k_main(
    const float* __restrict__ x, const float* __restrict__ hx, const float* __restrict__ cx,
    const float* __restrict__ bi, const float* __restrict__ bfm, const float* __restrict__ bg,
    const float* __restrict__ Uinv, const u16* __restrict__ RW, const u16* __restrict__ CW,
    const u16* __restrict__ Vtt, float* __restrict__ proj) {
  __shared__ u16 sA[Hh * LDA];   // 36864 B: A-side staging (RW rows / Vt_t rows)
  __shared__ u16 sB[KB * LDB];   //  5120 B: B-side staging (scaled CW rows)
  __shared__ u16 sP[Hh * LDA];   // 36864 B: tanh(zg) -> p -> c buffer [j][k]
  __shared__ float sV[KF];
  __shared__ float sR[Hh];

  const int tid  = threadIdx.x;
  const int b    = blockIdx.x >> 2;
  const int k0   = (blockIdx.x & 3) * KB;
  const int lane = tid & 63;
  const int w    = tid >> 6;
  const int r15  = lane & 15;
  const int quad = lane >> 4;

  if (tid < Ii) sV[tid] = x[b * Ii + tid];
  sV[Ii + tid] = hx[b * Hh + tid];

  f32x4 acc[4][4];

  for (int phase = 0; phase < 3; ++phase) {
    // gate order: g (tanh) first, then i, then f
    const int g = (phase == 0) ? 2 : (phase == 1 ? 0 : 1);
    const u16* rw = RW + g * Hh * KF;
    const u16* cw = CW + g * Hh * KF;
    const float* bias = (phase == 0) ? bg : (phase == 1 ? bi : bfm);

#pragma unroll
    for (int ti = 0; ti < 4; ++ti)
#pragma unroll
      for (int tk = 0; tk < 4; ++tk)
#pragma unroll
        for (int r = 0; r < 4; ++r) acc[ti][tk][r] = 0.0f;

    for (int kc = 0; kc < 12; ++kc) {
      __syncthreads();
      // stage A: raw copy RW[0:256, kc*32 : kc*32+32] (bf16)
#pragma unroll
      for (int rep = 0; rep < 4; ++rep) {
        int gi = rep * 256 + tid;
        int row = gi >> 2, cg = gi & 3;
        const uint4 d = *(const uint4*)(rw + row * KF + kc * 32 + cg * 8);
        *(uint4*)(&sA[row * LDA + cg * 8]) = d;
      }
      // stage B: CW[k0:k0+64, chunk] scaled by v_b (the diag of the sandwich)
      {
        int row = tid >> 2, cg = tid & 3;
        union { uint4 v; u16 u[8]; } in, ov;
        in.v = *(const uint4*)(cw + (k0 + row) * KF + kc * 32 + cg * 8);
#pragma unroll
        for (int e = 0; e < 8; ++e)
          ov.u[e] = f2bf(bf2f(in.u[e]) * sV[kc * 32 + cg * 8 + e]);
        *(uint4*)(&sB[row * LDB + cg * 8]) = ov.v;
      }
      __syncthreads();

      bf16x8 fa[4], fb[4];
#pragma unroll
      for (int ti = 0; ti < 4; ++ti)
        fa[ti] = *(const bf16x8*)(&sA[(w * 64 + ti * 16 + r15) * LDA + quad * 8]);
#pragma unroll
      for (int tk = 0; tk < 4; ++tk)
        fb[tk] = *(const bf16x8*)(&sB[(tk * 16 + r15) * LDB + quad * 8]);
#pragma unroll
      for (int ti = 0; ti < 4; ++ti)
#pragma unroll
        for (int tk = 0; tk < 4; ++tk)
          acc[ti][tk] = __builtin_amdgcn_mfma_f32_16x16x32_bf16(fa[ti], fb[tk], acc[ti][tk], 0, 0, 0);
    }

    // combine: C/D layout col=lane&15 (k), row=quad*4+reg (j)  [verified m89/m91]
#pragma unroll
    for (int ti = 0; ti < 4; ++ti) {
#pragma unroll
      for (int tk = 0; tk < 4; ++tk) {
#pragma unroll
        for (int r = 0; r < 4; ++r) {
          const int j = w * 64 + ti * 16 + quad * 4 + r;
          const int kk = tk * 16 + r15;
          float z = acc[ti][tk][r] + bias[j * Hh + k0 + kk];
          if (phase == 0) {
            sP[j * LDA + kk] = f2bf(tanh_f(z));
          } else if (phase == 1) {
            float p = sigm(z) * bf2f(sP[j * LDA + kk]);
            sP[j * LDA + kk] = f2bf(p);
          } else {
            float c = sigm(z) * cx[b * Hh * Hh + j * Hh + k0 + kk] + bf2f(sP[j * LDA + kk]);
            sP[j * LDA + kk] = f2bf(c);
          }
        }
      }
    }
  }

  // ---- down-projection: M[i,j] = sum_{k in block} Vt_t[i,k] * c[j,k] ----
  __syncthreads();
#pragma unroll
  for (int rep = 0; rep < 8; ++rep) {
    int gi = rep * 256 + tid;
    int row = gi >> 3, cg = gi & 7;
    *(uint4*)(&sA[row * LDA + cg * 8]) = *(const uint4*)(Vtt + row * Hh + k0 + cg * 8);
  }
  __syncthreads();

  float racc[4][4];
#pragma unroll
  for (int ti = 0; ti < 4; ++ti)
#pragma unroll
    for (int r = 0; r < 4; ++r) racc[ti][r] = 0.0f;

  for (int jt = 0; jt < 4; ++jt) {
#pragma unroll
    for (int ti = 0; ti < 4; ++ti)
#pragma unroll
      for (int tj = 0; tj < 4; ++tj)
#pragma unroll
        for (int r = 0; r < 4; ++r) acc[ti][tj][r] = 0.0f;
#pragma unroll
    for (int ks = 0; ks < 2; ++ks) {
      bf16x8 fa[4], fb[4];
#pragma unroll
      for (int ti = 0; ti < 4; ++ti)
        fa[ti] = *(const bf16x8*)(&sA[(w * 64 + ti * 16 + r15) * LDA + ks * 32 + quad * 8]);
#pragma unroll
      for (int tj = 0; tj < 4; ++tj)
        fb[tj] = *(const bf16x8*)(&sP[(jt * 64 + tj * 16 + r15) * LDA + ks * 32 + quad * 8]);
#pragma unroll
      for (int ti = 0; ti < 4; ++ti)
#pragma unroll
        for (int tj = 0; tj < 4; ++tj)
          acc[ti][tj] = __builtin_amdgcn_mfma_f32_16x16x32_bf16(fa[ti], fb[tj], acc[ti][tj], 0, 0, 0);
    }
    // weight by Uinv[i,j] and fold j into lane-local partials
#pragma unroll
    for (int ti = 0; ti < 4; ++ti)
#pragma unroll
      for (int tj = 0; tj < 4; ++tj)
#pragma unroll
        for (int r = 0; r < 4; ++r) {
          const int i  = w * 64 + ti * 16 + quad * 4 + r;
          const int jj = jt * 64 + tj * 16 + r15;
          racc[ti][r] += acc[ti][tj][r] * Uinv[i * Hh + jj];
        }
  }

  // reduce the 16 j-lanes of each quad, then one atomic per (b,i)
#pragma unroll
  for (int ti = 0; ti < 4; ++ti)
#pragma unroll
    for (int r = 0; r < 4; ++r) {
      float v = racc[ti][r];
      v += __shfl_xor(v, 1);
      v += __shfl_xor(v, 2);
      v += __shfl_xor(v, 4);
      v += __shfl_xor(v, 8);
      if (r15 == 0) sR[w * 64 + ti * 16 + quad * 4 + r] = v;
    }
  __syncthreads();
  atomicAdd(&proj[b * Hh + tid], sR[tid]);
}

// ---------------- kernel 2: o-gate + final output ---------------------------
__global__ __launch_bounds__(256) void k_out(const float* __restrict__ x, const float* __restrict__ hx,
                                             const float* __restrict__ Wio, const float* __restrict__ Who,
                                             const float* __restrict__ bo, const float* __restrict__ proj,
                                             float* __restrict__ out) {
  __shared__ float v[KF];
  const int b = blockIdx.x, h = threadIdx.x;
  if (h < Ii) v[h] = x[b * Ii + h];
  v[Ii + h] = hx[b * Hh + h];
  __syncthreads();
  float s = bo[h];
  for (int i = 0; i < Ii; ++i) s += Wio[h * Ii + i] * v[i];
  for (int j = 0; j < Hh; ++j) s += Who[h * Hh + j] * v[Ii + j];
  out[b * Hh + h] = sigm(s) * sigm(proj[b * Hh + h]);
}

extern "C" void kernel_launch(void* const* d_in, const int* in_sizes, int n_in,
                              void* d_out, int out_size, void* d_ws, size_t ws_size,
                              hipStream_t stream) {
  const float* x    = (const float*)d_in[0];
  const float* hx   = (const float*)d_in[1];
  const float* cx   = (const float*)d_in[2];
  const float* Wii  = (const float*)d_in[3];
  const float* Wif  = (const float*)d_in[4];
  const float* Wig  = (const float*)d_in[5];
  const float* Wio  = (const float*)d_in[6];
  const float* Whi  = (const float*)d_in[7];
  const float* Whit = (const float*)d_in[8];
  const float* Whf  = (const float*)d_in[9];
  const float* Whft = (const float*)d_in[10];
  const float* Whc  = (const float*)d_in[11];
  const float* Whct = (const float*)d_in[12];
  const float* Who  = (const float*)d_in[13];
  const float* Uinv = (const float*)d_in[14];
  const float* Vtinv= (const float*)d_in[15];
  const float* bi   = (const float*)d_in[16];
  const float* bf   = (const float*)d_in[17];
  const float* bg   = (const float*)d_in[18];
  const float* bo   = (const float*)d_in[19];
  float* out = (float*)d_out;

  // workspace layout (~1.75 MB): RW[3], CW[3] bf16; Vtt bf16; proj f32
  u16* RW  = (u16*)d_ws;
  u16* CW  = RW + 3 * Hh * KF;
  u16* Vtt = CW + 3 * Hh * KF;
  float* proj = (float*)(Vtt + Hh * Hh);

  k_prep<<<1152, 256, 0, stream>>>(Wii, Wif, Wig, Whi, Whit, Whf, Whft, Whc, Whct,
                                   Vtinv, RW, CW, Vtt, proj);
  k_main<<<2048, 256, 0, stream>>>(x, hx, cx, bi, bf, bg, Uinv, RW, CW, Vtt, proj);
  k_out<<<512, 256, 0, stream>>>(x, hx, Wio, Who, bo, proj, out);
}

// Round 2
// 582.731 us; speedup vs baseline: 1.1710x; 1.1710x over previous
//
#include <hip/hip_runtime.h>

#define Hh 256
#define Ii 128
#define Bb 512
#define KF 384   // 128 (x) + 256 (hx) feature dim
#define KB 64    // k-block width per block
#define LDB 40   // padded LDS stride for sB (bf16 elems)

typedef __attribute__((ext_vector_type(8))) short bf16x8;
typedef __attribute__((ext_vector_type(4))) float f32x4;
typedef unsigned short u16;
typedef unsigned int u32;

__device__ inline float bf2f(u16 u) { return __uint_as_float(((u32)u) << 16); }
__device__ inline u16 f2bf(float f) {
  u32 u = __float_as_uint(f);
  u += 0x7FFFu + ((u >> 16) & 1u);   // RNE
  return (u16)(u >> 16);
}
__device__ inline float sigm(float x) { return 1.0f / (1.0f + __expf(-x)); }
__device__ inline float tanh_f(float x) { return 1.0f - 2.0f / (1.0f + __expf(2.0f * x)); }

// sP swizzle: element (j, kk) -> j*64 + ((kk>>3 ^ (j&7))<<3 | (kk&7)); keeps
// 8-elem chunks contiguous (b128-able) while spreading banks. 32 KB, no pad.
__device__ inline int sp_idx(int j, int kk) {
  return j * 64 + ((((kk >> 3) ^ (j & 7)) << 3) | (kk & 7));
}

// ---------------- kernel 0: pack bf16 weights, transpose Vtinv, zero proj ----
__global__ __launch_bounds__(256) void k_prep(
    const float* __restrict__ Wii, const float* __restrict__ Wif, const float* __restrict__ Wig,
    const float* __restrict__ Whi, const float* __restrict__ Whit,
    const float* __restrict__ Whf, const float* __restrict__ Whft,
    const float* __restrict__ Whc, const float* __restrict__ Whct,
    const float* __restrict__ Vtinv,
    u16* __restrict__ RW, u16* __restrict__ CW, u16* __restrict__ Vtt,
    float* __restrict__ proj) {
  const int tid = threadIdx.x, bx = blockIdx.x, y = blockIdx.y;
  if (y < 3) {
    const float* WX  = (y == 0) ? Wii : (y == 1 ? Wif : Wig);
    const float* WHr = (y == 0) ? Whi : (y == 1 ? Whf : Whc);
    const float* WHt = (y == 0) ? Whit : (y == 1 ? Whft : Whct);
    u16* rw = RW + y * Hh * KF;
    u16* cw = CW + y * Hh * KF;
#pragma unroll
    for (int it = 0; it < 4; ++it) {
      int idx = it * 24576 + bx * 256 + tid;   // 0..98303
      int h = idx / KF, t = idx - h * KF;
      float a, c;
      if (t < Ii) { a = WX[h * Ii + t]; c = a; }
      else        { a = WHr[h * Hh + t - Ii]; c = WHt[h * Hh + t - Ii]; }
      rw[idx] = f2bf(a);
      cw[idx] = f2bf(c);
    }
  } else if (bx < 64) {
    // Vtt[i][k] = Vtinv[k][i], 32x32 LDS tile transpose (coalesced both sides)
    __shared__ u16 tbuf[32][33];
    const int c = tid & 31, r8 = tid >> 5;
    const int tr = bx >> 3, tc = bx & 7;
#pragma unroll
    for (int rr = r8; rr < 32; rr += 8)
      tbuf[rr][c] = f2bf(Vtinv[(tc * 32 + rr) * Hh + tr * 32 + c]);
    __syncthreads();
#pragma unroll
    for (int rr = r8; rr < 32; rr += 8)
      Vtt[(tr * 32 + rr) * Hh + tc * 32 + c] = tbuf[c][rr];
  } else {
    // zero proj: 32 blocks x 256 threads x 4 x float4 = 131072 floats
    const int base = (bx - 64) * 256 + tid;
    const float4 z = {0.f, 0.f, 0.f, 0.f};
#pragma unroll
    for (int it = 0; it < 4; ++it)
      *(float4*)(proj + (size_t)(it * 8192 + base) * 4) = z;
  }
}

// ---------------- gate pass (one of three phases) ----------------------------
// PHASE 0: p  = tanh(zg)                       (gate g)
// PHASE 1: p *= sigmoid(zi)                    (gate i)
// PHASE 2: c  = sigmoid(zf)*cx + p             (gate f)
template <int PHASE>
__device__ __forceinline__ void gate_pass(
    const u16* __restrict__ rw, const u16* __restrict__ cw,
    const float* __restrict__ bias, const float* __restrict__ cx_b,
    u16* sP, u16* sB, const float* sV, int tid, int k0) {
  const int lane = tid & 63, w = tid >> 6;
  const int r15 = lane & 15, quad = lane >> 4;
  const int brow = tid >> 2, bcg = tid & 3;

  f32x4 acc[4][4];
#pragma unroll
  for (int ti = 0; ti < 4; ++ti)
#pragma unroll
    for (int tk = 0; tk < 4; ++tk)
#pragma unroll
      for (int r = 0; r < 4; ++r) acc[ti][tk][r] = 0.0f;

  // prologue: chunk 0 loads
  uint4 bnx = *(const uint4*)(cw + (k0 + brow) * KF + bcg * 8);
  bf16x8 fa[4];
#pragma unroll
  for (int ti = 0; ti < 4; ++ti)
    fa[ti] = *(const bf16x8*)(rw + (w * 64 + ti * 16 + r15) * KF + quad * 8);
  if (PHASE == 0) __syncthreads();   // sV ready (later phases: covered by prior barrier)
  {
    union { uint4 v; u16 u[8]; } in, ov;
    in.v = bnx;
    const float4 v0 = *(const float4*)(&sV[bcg * 8]);
    const float4 v1 = *(const float4*)(&sV[bcg * 8 + 4]);
    const float vs[8] = {v0.x, v0.y, v0.z, v0.w, v1.x, v1.y, v1.z, v1.w};
#pragma unroll
    for (int e = 0; e < 8; ++e) ov.u[e] = f2bf(bf2f(in.u[e]) * vs[e]);
    *(uint4*)(sB + brow * LDB + bcg * 8) = ov.v;
  }
  __syncthreads();                   // sB[0] ready

#pragma unroll
  for (int kc = 0; kc < 12; ++kc) {
    const int cur = kc & 1, nxt = cur ^ 1;
    uint4 bnx2;
    bf16x8 fan[4];
    if (kc < 11) {
      bnx2 = *(const uint4*)(cw + (k0 + brow) * KF + (kc + 1) * 32 + bcg * 8);
#pragma unroll
      for (int ti = 0; ti < 4; ++ti)
        fan[ti] = *(const bf16x8*)(rw + (w * 64 + ti * 16 + r15) * KF + (kc + 1) * 32 + quad * 8);
    }
    bf16x8 fb[4];
#pragma unroll
    for (int tk = 0; tk < 4; ++tk)
      fb[tk] = *(const bf16x8*)(&sB[cur * (KB * LDB) + (tk * 16 + r15) * LDB + quad * 8]);
#pragma unroll
    for (int ti = 0; ti < 4; ++ti)
#pragma unroll
      for (int tk = 0; tk < 4; ++tk)
        acc[ti][tk] = __builtin_amdgcn_mfma_f32_16x16x32_bf16(fa[ti], fb[tk], acc[ti][tk], 0, 0, 0);
    if (kc < 11) {
      union { uint4 v; u16 u[8]; } in, ov;
      in.v = bnx2;
      const float4 v0 = *(const float4*)(&sV[(kc + 1) * 32 + bcg * 8]);
      const float4 v1 = *(const float4*)(&sV[(kc + 1) * 32 + bcg * 8 + 4]);
      const float vs[8] = {v0.x, v0.y, v0.z, v0.w, v1.x, v1.y, v1.z, v1.w};
#pragma unroll
      for (int e = 0; e < 8; ++e) ov.u[e] = f2bf(bf2f(in.u[e]) * vs[e]);
      *(uint4*)(sB + nxt * (KB * LDB) + brow * LDB + bcg * 8) = ov.v;
#pragma unroll
      for (int ti = 0; ti < 4; ++ti) fa[ti] = fan[ti];
    }
    __syncthreads();
  }

  // combine: C/D layout col(kk)=lane&15, row(j)=quad*4+reg — thread-local sP RMW
#pragma unroll
  for (int ti = 0; ti < 4; ++ti) {
#pragma unroll
    for (int tk = 0; tk < 4; ++tk) {
#pragma unroll
      for (int r = 0; r < 4; ++r) {
        const int j = w * 64 + ti * 16 + quad * 4 + r;
        const int kk = tk * 16 + r15;
        const int si = sp_idx(j, kk);
        float z = acc[ti][tk][r] + bias[j * Hh + k0 + kk];
        if (PHASE == 0) {
          sP[si] = f2bf(tanh_f(z));
        } else if (PHASE == 1) {
          sP[si] = f2bf(sigm(z) * bf2f(sP[si]));
        } else {
          sP[si] = f2bf(sigm(z) * cx_b[j * Hh + k0 + kk] + bf2f(sP[si]));
        }
      }
    }
  }
}

// ---------------- kernel 1: fused gates + cell + down-projection -------------
__global__ __launch_bounds__(256, 3) void k_main(
    const float* __restrict__ x, const float* __restrict__ hx, const float* __restrict__ cx,
    const float* __restrict__ bi, const float* __restrict__ bfm, const float* __restrict__ bg,
    const float* __restrict__ Uinv, const u16* __restrict__ RW, const u16* __restrict__ CW,
    const u16* __restrict__ Vtt, float* __restrict__ proj) {
  __shared__ u16 sP[Hh * 64];        // 32768 B, XOR-swizzled c-buffer [j][kk]
  __shared__ u16 sB[2 * KB * LDB];   // 10240 B, double-buffered scaled-B
  __shared__ float sV[KF];           //  1536 B

  const int tid  = threadIdx.x;
  const int b    = blockIdx.x >> 2;
  const int k0   = (blockIdx.x & 3) * KB;
  const int lane = tid & 63;
  const int w    = tid >> 6;
  const int r15  = lane & 15;
  const int quad = lane >> 4;

  if (tid < Ii) sV[tid] = x[b * Ii + tid];
  sV[Ii + tid] = hx[b * Hh + tid];

  const float* cx_b = cx + (size_t)b * Hh * Hh;
  gate_pass<0>(RW + 2 * Hh * KF, CW + 2 * Hh * KF, bg,  cx_b, sP, sB, sV, tid, k0);
  gate_pass<1>(RW + 0 * Hh * KF, CW + 0 * Hh * KF, bi,  cx_b, sP, sB, sV, tid, k0);
  gate_pass<2>(RW + 1 * Hh * KF, CW + 1 * Hh * KF, bfm, cx_b, sP, sB, sV, tid, k0);

  __syncthreads();   // sP (c-tile) complete for cross-thread reads

  // ---- down-projection: M[i,j] = sum_{k in block} Vt_t[i,k] * c[j,k] ----
  bf16x8 va[4][2];
#pragma unroll
  for (int ti = 0; ti < 4; ++ti)
#pragma unroll
    for (int ks = 0; ks < 2; ++ks)
      va[ti][ks] = *(const bf16x8*)(Vtt + (w * 64 + ti * 16 + r15) * Hh + k0 + ks * 32 + quad * 8);

  float racc[4][4];
#pragma unroll
  for (int ti = 0; ti < 4; ++ti)
#pragma unroll
    for (int r = 0; r < 4; ++r) racc[ti][r] = 0.0f;

  for (int jt = 0; jt < 4; ++jt) {
    f32x4 pacc[4][4];
#pragma unroll
    for (int ti = 0; ti < 4; ++ti)
#pragma unroll
      for (int tj = 0; tj < 4; ++tj)
#pragma unroll
        for (int r = 0; r < 4; ++r) pacc[ti][tj][r] = 0.0f;
#pragma unroll
    for (int ks = 0; ks < 2; ++ks) {
      bf16x8 fbp[4];
#pragma unroll
      for (int tj = 0; tj < 4; ++tj) {
        const int j = jt * 64 + tj * 16 + r15;
        const int ch = (ks * 4 + quad) ^ (j & 7);
        fbp[tj] = *(const bf16x8*)(&sP[j * 64 + ch * 8]);
      }
#pragma unroll
      for (int ti = 0; ti < 4; ++ti)
#pragma unroll
        for (int tj = 0; tj < 4; ++tj)
          pacc[ti][tj] = __builtin_amdgcn_mfma_f32_16x16x32_bf16(va[ti][ks], fbp[tj], pacc[ti][tj], 0, 0, 0);
    }
#pragma unroll
    for (int ti = 0; ti < 4; ++ti)
#pragma unroll
      for (int tj = 0; tj < 4; ++tj)
#pragma unroll
        for (int r = 0; r < 4; ++r) {
          const int i  = w * 64 + ti * 16 + quad * 4 + r;
          const int jj = jt * 64 + tj * 16 + r15;
          racc[ti][r] += pacc[ti][tj][r] * Uinv[i * Hh + jj];
        }
  }

#pragma unroll
  for (int ti = 0; ti < 4; ++ti)
#pragma unroll
    for (int r = 0; r < 4; ++r) {
      float v = racc[ti][r];
      v += __shfl_xor(v, 1);
      v += __shfl_xor(v, 2);
      v += __shfl_xor(v, 4);
      v += __shfl_xor(v, 8);
      if (r15 == 0) atomicAdd(&proj[b * Hh + w * 64 + ti * 16 + quad * 4 + r], v);
    }
}

// ---------------- kernel 2: o-gate + final output ---------------------------
__global__ __launch_bounds__(256) void k_out(
    const float* __restrict__ x, const float* __restrict__ hx,
    const float* __restrict__ Wio, const float* __restrict__ Who,
    const float* __restrict__ bo, const float* __restrict__ proj,
    float* __restrict__ out) {
  __shared__ float sv[KF];
  const int b = blockIdx.x, tid = threadIdx.x;
  const int lane = tid & 63, w = tid >> 6;
  if (tid < Ii) sv[tid] = x[b * Ii + tid];
  sv[Ii + tid] = hx[b * Hh + tid];
  __syncthreads();
  // wave w owns rows h = w*64 .. w*64+63; coalesced 64-lane row reads
  for (int rr = 0; rr < 64; ++rr) {
    const int h = w * 64 + rr;
    float p = Wio[h * Ii + lane]        * sv[lane]
            + Wio[h * Ii + 64 + lane]   * sv[64 + lane]
            + Who[h * Hh + lane]        * sv[128 + lane]
            + Who[h * Hh + 64 + lane]   * sv[192 + lane]
            + Who[h * Hh + 128 + lane]  * sv[256 + lane]
            + Who[h * Hh + 192 + lane]  * sv[320 + lane];
    p += __shfl_xor(p, 32);
    p += __shfl_xor(p, 16);
    p += __shfl_xor(p, 8);
    p += __shfl_xor(p, 4);
    p += __shfl_xor(p, 2);
    p += __shfl_xor(p, 1);
    if (lane == 0)
      out[b * Hh + h] = sigm(p + bo[h]) * sigm(proj[b * Hh + h]);
  }
}

extern "C" void kernel_launch(void* const* d_in, const int* in_sizes, int n_in,
                              void* d_out, int out_size, void* d_ws, size_t ws_size,
                              hipStream_t stream) {
  (void)in_sizes; (void)n_in; (void)out_size; (void)ws_size;
  const float* x    = (const float*)d_in[0];
  const float* hx   = (const float*)d_in[1];
  const float* cx   = (const float*)d_in[2];
  const float* Wii  = (const float*)d_in[3];
  const float* Wif  = (const float*)d_in[4];
  const float* Wig  = (const float*)d_in[5];
  const float* Wio  = (const float*)d_in[6];
  const float* Whi  = (const float*)d_in[7];
  const float* Whit = (const float*)d_in[8];
  const float* Whf  = (const float*)d_in[9];
  const float* Whft = (const float*)d_in[10];
  const float* Whc  = (const float*)d_in[11];
  const float* Whct = (const float*)d_in[12];
  const float* Who  = (const float*)d_in[13];
  const float* Uinv = (const float*)d_in[14];
  const float* Vtinv= (const float*)d_in[15];
  const float* bi   = (const float*)d_in[16];
  const float* bf   = (const float*)d_in[17];
  const float* bg   = (const float*)d_in[18];
  const float* bo   = (const float*)d_in[19];
  float* out = (float*)d_out;

  // workspace layout (~1.83 MB): RW[3], CW[3] bf16; Vtt bf16; proj f32
  u16* RW  = (u16*)d_ws;
  u16* CW  = RW + 3 * Hh * KF;
  u16* Vtt = CW + 3 * Hh * KF;
  float* proj = (float*)(Vtt + Hh * Hh);

  k_prep<<<dim3(96, 4), 256, 0, stream>>>(Wii, Wif, Wig, Whi, Whit, Whf, Whft, Whc, Whct,
                                          Vtinv, RW, CW, Vtt, proj);
  k_main<<<2048, 256, 0, stream>>>(x, hx, cx, bi, bf, bg, Uinv, RW, CW, Vtt, proj);
  k_out<<<512, 256, 0, stream>>>(x, hx, Wio, Who, bo, proj, out);
}